// Round 4
// baseline (52.076 us; speedup 1.0000x reference)
//
#include <hip/hip_runtime.h>

// TensorFusion: out = relu(relu(fused @ W1 + b1) @ W2 + b2) @ W3 + b3
// fused[b, i*1024+j*32+k] = z0[b,i]*z1[b,j]*z2[b,k], z* = [x*, 1]
// B=256, D=31 (+1 bias col -> 32), FUSED=32768, H1=1024, H2=256, NCLS=4

typedef _Float16 half8 __attribute__((ext_vector_type(8)));
typedef _Float16 half4 __attribute__((ext_vector_type(4)));
typedef _Float16 half2 __attribute__((ext_vector_type(2)));
typedef float f32x4 __attribute__((ext_vector_type(4)));

#define KSPLIT 16

// ---------------------------------------------------------------------------
// K1: partial[ks][b][h] = sum over 2048-K-chunk of fused[b,k] * W1[k,h]
// grid = 32 ntiles * 16 ksplit = 512 blocks (2/CU), 512 threads (8 waves).
// Block tile M=256 x N=32; wave w: rows [w*32, w*32+32), full N.
// Pipeline: W1 f32 -> regs (4 tiles deep, 8 outstanding dwords/wave)
//   -> cvt f16 -> swizzled ds_write -> LDS [n][k] f16 ring of 4 bufs.
// Raw lgkmcnt(0)+s_barrier per step (no vmcnt drain); compiler emits
// counted vmcnt for the reg pipeline.
// ---------------------------------------------------------------------------
__global__ __launch_bounds__(512, 4) void k1_gemm(
    const float* __restrict__ x0, const float* __restrict__ x1,
    const float* __restrict__ x2, const float* __restrict__ W1,
    float* __restrict__ partial)
{
    constexpr int GRPS = 16;                 // 64 steps / 4
    __shared__ __align__(16) _Float16 z01L[GRPS][256][4];  // 32 KB
    __shared__ __align__(16) _Float16 tile[4][1024];       // 4 x 2KB, [n][k] swz

    const int tid  = threadIdx.x;
    const int nt   = blockIdx.x & 31;
    const int ks   = blockIdx.x >> 5;
    const int lane = tid & 63;
    const int w    = tid >> 6;        // wave 0..7
    const int nl   = lane & 15;
    const int g    = lane >> 4;       // 0..3
    const int kbase = ks * 2048;
    const int n0    = nt * 32;

    // ---- z01 table: pair p (0..63): i = ks*2 + (p>>5), j = p&31
    {
        const int b  = tid & 255;
        const int hf = tid >> 8;              // 0..1
        const int i  = ks * 2 + hf;
        const float v0 = (i < 31) ? x0[b * 31 + i] : 1.0f;
#pragma unroll
        for (int pp = 0; pp < 32; pp += 4) {
            half4 hv;
#pragma unroll
            for (int e = 0; e < 4; ++e) {
                int j = pp + e;
                float v1 = (j < 31) ? x1[b * 31 + j] : 1.0f;
                hv[e] = (_Float16)(v0 * v1);
            }
            *(half4*)&z01L[(hf * 32 + pp) >> 2][b][0] = hv;
        }
    }

    // ---- z2 register fragments (A-operand k-axis), 2 M-subtiles per wave
    half8 z2v[2];
#pragma unroll
    for (int ms = 0; ms < 2; ++ms) {
        int b = w * 32 + ms * 16 + nl;
#pragma unroll
        for (int e = 0; e < 8; ++e) {
            int kp = g * 8 + e;
            z2v[ms][e] = (_Float16)((kp < 31) ? x2[b * 31 + kp] : 1.0f);
        }
    }

    // ---- staging map: thread -> (col sn, k-pair sk2): 2 dwords per tile
    const int sn  = tid & 31;
    const int sk2 = tid >> 5;                 // 0..15 -> rows sk2*2, sk2*2+1
    const float* gsrc = W1 + (size_t)(kbase + sk2 * 2) * 1024 + n0 + sn;
    const int wswz = (((sn & 7) ^ (sn >> 3)) & 7) << 2;   // 4-f16 granule XOR
    const int woff = sn * 32 + ((sk2 * 2) ^ wswz);

    // ---- B-fragment read offsets (f16 idx), literal-indexed after unroll
    int roff[2][2];
#pragma unroll
    for (int ns = 0; ns < 2; ++ns) {
        int n = ns * 16 + nl;
        int s = (((n & 7) ^ (n >> 3)) & 7) << 2;
        roff[ns][0] = n * 32 + ((g * 8) ^ s);
        roff[ns][1] = n * 32 + ((g * 8 + 4) ^ s);
    }

    __syncthreads();   // z01L ready (full drain OK here, nothing in flight)

    // ---- prologue: fill 4-deep register pipeline (tiles 0..3)
    float rxv[4], ryv[4];
#pragma unroll
    for (int s = 0; s < 4; ++s) {
        rxv[s] = gsrc[(size_t)s * 32768];
        ryv[s] = gsrc[(size_t)s * 32768 + 1024];
    }
    {   // write tile 0 -> buf 0 (compiler inserts counted vmcnt)
        half2 hv; hv[0] = (_Float16)rxv[0]; hv[1] = (_Float16)ryv[0];
        *(half2*)&tile[0][woff] = hv;
    }
    asm volatile("s_waitcnt lgkmcnt(0)\n\ts_barrier" ::: "memory");

    f32x4 acc[2][2] = {};
    half4 zq0, zq1;

    // Per step T_: compute tile T_ (buf T_&3); issue loads tile T_+4 into
    // reg slot TT; cvt+write tile T_+1 (slot (TT+1)&3) AFTER the MFMAs so
    // the vmcnt wait overlaps compute; barrier gates next iter's reads.
#define ITER(T_, TT, ISSUE, WRITE)                                             \
    {                                                                          \
        if (ISSUE) {                                                           \
            rxv[TT] = gsrc[(size_t)((T_) + 4) * 32768];                        \
            ryv[TT] = gsrc[(size_t)((T_) + 4) * 32768 + 1024];                 \
        }                                                                      \
        if ((TT) == 0) {                                                       \
            zq0 = *(const half4*)&z01L[(T_) >> 2][w * 32 + nl][0];             \
            zq1 = *(const half4*)&z01L[(T_) >> 2][w * 32 + 16 + nl][0];        \
        }                                                                      \
        const _Float16* tb = &tile[(T_) & 3][0];                               \
        half4 lo0 = *(const half4*)&tb[roff[0][0]];                            \
        half4 hi0 = *(const half4*)&tb[roff[0][1]];                            \
        half4 lo1 = *(const half4*)&tb[roff[1][0]];                            \
        half4 hi1 = *(const half4*)&tb[roff[1][1]];                            \
        half8 bh0 = __builtin_shufflevector(lo0, hi0, 0,1,2,3,4,5,6,7);        \
        half8 bh1 = __builtin_shufflevector(lo1, hi1, 0,1,2,3,4,5,6,7);        \
        half8 a0 = z2v[0] * zq0[TT];                                           \
        half8 a1 = z2v[1] * zq1[TT];                                           \
        acc[0][0] = __builtin_amdgcn_mfma_f32_16x16x32_f16(a0, bh0, acc[0][0], 0, 0, 0); \
        acc[0][1] = __builtin_amdgcn_mfma_f32_16x16x32_f16(a0, bh1, acc[0][1], 0, 0, 0); \
        acc[1][0] = __builtin_amdgcn_mfma_f32_16x16x32_f16(a1, bh0, acc[1][0], 0, 0, 0); \
        acc[1][1] = __builtin_amdgcn_mfma_f32_16x16x32_f16(a1, bh1, acc[1][1], 0, 0, 0); \
        if (WRITE) {                                                           \
            half2 hv;                                                          \
            hv[0] = (_Float16)rxv[((TT) + 1) & 3];                             \
            hv[1] = (_Float16)ryv[((TT) + 1) & 3];                             \
            *(half2*)&tile[((T_) + 1) & 3][woff] = hv;                         \
        }                                                                      \
        asm volatile("s_waitcnt lgkmcnt(0)\n\ts_barrier" ::: "memory");        \
    }

    for (int grp = 0; grp < 15; ++grp) {
        const int t = grp * 4;
        ITER(t + 0, 0, 1, 1)
        ITER(t + 1, 1, 1, 1)
        ITER(t + 2, 2, 1, 1)
        ITER(t + 3, 3, 1, 1)
    }
    ITER(60, 0, 0, 1)
    ITER(61, 1, 0, 1)
    ITER(62, 2, 0, 1)
    ITER(63, 3, 0, 0)
#undef ITER

    // ---- epilogue: D layout col = lane&15, row = (lane>>4)*4 + r
    float* pout = partial + (size_t)ks * (256 * 1024);
#pragma unroll
    for (int ms = 0; ms < 2; ++ms)
#pragma unroll
        for (int ns = 0; ns < 2; ++ns)
#pragma unroll
            for (int r = 0; r < 4; ++r) {
                int brow = w * 32 + ms * 16 + g * 4 + r;
                int ncol = n0 + ns * 16 + nl;
                pout[brow * 1024 + ncol] = acc[ms][ns][r];
            }
}

// ---------------------------------------------------------------------------
// K2: h1[e] = relu(sum_s partial[s][e] + b1[e%1024]); h1 aliases partial[0]
// ---------------------------------------------------------------------------
__global__ __launch_bounds__(256) void k2_reduce(
    const float* __restrict__ partial, const float* __restrict__ b1,
    float* __restrict__ h1)
{
    int e = blockIdx.x * 256 + threadIdx.x;   // grid 1024 -> 262144 elements
    float s = 0.f;
#pragma unroll
    for (int sp = 0; sp < KSPLIT; ++sp) s += partial[(size_t)sp * 262144 + e];
    s += b1[e & 1023];
    h1[e] = fmaxf(s, 0.f);
}

// ---------------------------------------------------------------------------
// K3: layer 2 partials, M=256 K=1024 N=256; Mtile=32 Ntile=64 Ksplit=8
// ---------------------------------------------------------------------------
__global__ __launch_bounds__(256) void k3_layer2(
    const float* __restrict__ h1, const float* __restrict__ W2,
    float* __restrict__ p2)
{
    __shared__ float h1t[32 * 129];
    __shared__ float w2t[128 * 65];
    const int tid = threadIdx.x;
    const int m0 = blockIdx.x * 32, n0 = blockIdx.y * 64, k0 = blockIdx.z * 128;

    for (int idx = tid; idx < 32 * 128; idx += 256) {
        int m = idx >> 7, kk = idx & 127;
        h1t[m * 129 + kk] = h1[(m0 + m) * 1024 + k0 + kk];
    }
    for (int idx = tid; idx < 128 * 64; idx += 256) {
        int kk = idx >> 6, n = idx & 63;
        w2t[kk * 65 + n] = W2[(k0 + kk) * 256 + n0 + n];
    }
    __syncthreads();

    const int tn = tid & 63, tm = tid >> 6;   // tm 0..3
    float acc[8] = {};
    for (int kk = 0; kk < 128; ++kk) {
        float w = w2t[kk * 65 + tn];
#pragma unroll
        for (int r = 0; r < 8; ++r)
            acc[r] += h1t[(tm * 8 + r) * 129 + kk] * w;
    }
#pragma unroll
    for (int r = 0; r < 8; ++r)
        p2[blockIdx.z * 65536 + (m0 + tm * 8 + r) * 256 + n0 + tn] = acc[r];
}

// ---------------------------------------------------------------------------
// K4: h2 = relu(sum_s p2[s] + b2); out = h2 @ W3 + b3. One block per sample.
// ---------------------------------------------------------------------------
__global__ __launch_bounds__(256) void k4_final(
    const float* __restrict__ p2, const float* __restrict__ b2,
    const float* __restrict__ W3, const float* __restrict__ b3,
    float* __restrict__ out)
{
    __shared__ float pL[256 * 5];
    const int b = blockIdx.x, n = threadIdx.x;
    float s = 0.f;
#pragma unroll
    for (int sp = 0; sp < 8; ++sp) s += p2[sp * 65536 + b * 256 + n];
    float h2 = fmaxf(s + b2[n], 0.f);
#pragma unroll
    for (int c = 0; c < 4; ++c) pL[n * 5 + c] = h2 * W3[n * 4 + c];
    __syncthreads();

    const int lane = n & 63, w = n >> 6;      // wave w handles class c=w
    float v = pL[lane * 5 + w] + pL[(lane + 64) * 5 + w] +
              pL[(lane + 128) * 5 + w] + pL[(lane + 192) * 5 + w];
#pragma unroll
    for (int off = 32; off > 0; off >>= 1) v += __shfl_down(v, off);
    if (lane == 0) out[b * 4 + w] = v + b3[w];
}

extern "C" void kernel_launch(void* const* d_in, const int* in_sizes, int n_in,
                              void* d_out, int out_size, void* d_ws, size_t ws_size,
                              hipStream_t stream)
{
    (void)in_sizes; (void)n_in; (void)out_size; (void)ws_size;
    const float* x0 = (const float*)d_in[0];
    const float* x1 = (const float*)d_in[1];
    const float* x2 = (const float*)d_in[2];
    const float* W1 = (const float*)d_in[3];
    const float* b1 = (const float*)d_in[4];
    const float* W2 = (const float*)d_in[5];
    const float* b2 = (const float*)d_in[6];
    const float* W3 = (const float*)d_in[7];
    const float* b3 = (const float*)d_in[8];
    float* out = (float*)d_out;
    float* ws  = (float*)d_ws;

    // ws layout (floats): partial[16][262144] f32 = 16.8 MB (ws >= 33.5 MB
    // verified in R2). h1 aliases partial[0] (thread reads its own element
    // before overwriting); p2[8][65536] aliases partial[1] (dead after k2).
    float* partial = ws;
    float* h1 = ws;
    float* p2 = ws + 262144;

    k1_gemm  <<<dim3(512),     dim3(512), 0, stream>>>(x0, x1, x2, W1, partial);
    k2_reduce<<<dim3(1024),    dim3(256), 0, stream>>>(partial, b1, h1);
    k3_layer2<<<dim3(8, 4, 8), dim3(256), 0, stream>>>(h1, W2, p2);
    k4_final <<<dim3(256),     dim3(256), 0, stream>>>(p2, b2, W3, b3, out);
}

// Round 5
// 51.762 us; speedup vs baseline: 1.0061x; 1.0061x over previous
//
#include <hip/hip_runtime.h>

// TensorFusion: out = relu(relu(fused @ W1 + b1) @ W2 + b2) @ W3 + b3
// fused[b, i*1024+j*32+k] = z0[b,i]*z1[b,j]*z2[b,k], z* = [x*, 1]
// B=256, D=31 (+1 bias col -> 32), FUSED=32768, H1=1024, H2=256, NCLS=4

typedef _Float16 half8 __attribute__((ext_vector_type(8)));
typedef _Float16 half4 __attribute__((ext_vector_type(4)));
typedef _Float16 half2 __attribute__((ext_vector_type(2)));
typedef float f32x4 __attribute__((ext_vector_type(4)));

#define KSPLIT 16

// ---------------------------------------------------------------------------
// K1: partial[ks][b][h] = sum over 2048-K-chunk of fused[b,k] * W1[k,h]
// grid = 32 ntiles * 16 ksplit = 512 blocks (2/CU), 512 threads (8 waves).
// Block tile M=256 x N=32; wave w: rows [w*32, w*32+32), full N.
// Pipeline: W1 f32 -> regs (4 tiles deep, 8 outstanding dwords/wave)
//   -> cvt f16 -> swizzled ds_write -> LDS [n][k] f16 ring of 4 bufs.
// Raw lgkmcnt(0)+s_barrier per step (no vmcnt drain); compiler emits
// counted vmcnt for the reg pipeline.
// ---------------------------------------------------------------------------
__global__ __launch_bounds__(512, 4) void k1_gemm(
    const float* __restrict__ x0, const float* __restrict__ x1,
    const float* __restrict__ x2, const float* __restrict__ W1,
    float* __restrict__ partial)
{
    constexpr int GRPS = 16;                 // 64 steps / 4
    __shared__ __align__(16) _Float16 z01L[GRPS][256][4];  // 32 KB
    __shared__ __align__(16) _Float16 tile[4][1024];       // 4 x 2KB, [n][k] swz

    const int tid  = threadIdx.x;
    const int nt   = blockIdx.x & 31;
    const int ks   = blockIdx.x >> 5;
    const int lane = tid & 63;
    const int w    = tid >> 6;        // wave 0..7
    const int nl   = lane & 15;
    const int g    = lane >> 4;       // 0..3
    const int kbase = ks * 2048;
    const int n0    = nt * 32;

    // ---- z01 table: pair p (0..63): i = ks*2 + (p>>5), j = p&31
    {
        const int b  = tid & 255;
        const int hf = tid >> 8;              // 0..1
        const int i  = ks * 2 + hf;
        const float v0 = (i < 31) ? x0[b * 31 + i] : 1.0f;
#pragma unroll
        for (int pp = 0; pp < 32; pp += 4) {
            half4 hv;
#pragma unroll
            for (int e = 0; e < 4; ++e) {
                int j = pp + e;
                float v1 = (j < 31) ? x1[b * 31 + j] : 1.0f;
                hv[e] = (_Float16)(v0 * v1);
            }
            *(half4*)&z01L[(hf * 32 + pp) >> 2][b][0] = hv;
        }
    }

    // ---- z2 register fragments (A-operand k-axis), 2 M-subtiles per wave
    half8 z2v[2];
#pragma unroll
    for (int ms = 0; ms < 2; ++ms) {
        int b = w * 32 + ms * 16 + nl;
#pragma unroll
        for (int e = 0; e < 8; ++e) {
            int kp = g * 8 + e;
            z2v[ms][e] = (_Float16)((kp < 31) ? x2[b * 31 + kp] : 1.0f);
        }
    }

    // ---- staging map: thread -> (col sn, k-pair sk2): 2 dwords per tile
    const int sn  = tid & 31;
    const int sk2 = tid >> 5;                 // 0..15 -> rows sk2*2, sk2*2+1
    const float* gsrc = W1 + (size_t)(kbase + sk2 * 2) * 1024 + n0 + sn;
    const int wswz = (((sn & 7) ^ (sn >> 3)) & 7) << 2;   // 4-f16 granule XOR
    const int woff = sn * 32 + ((sk2 * 2) ^ wswz);

    // ---- B-fragment read offsets (f16 idx), literal-indexed after unroll
    int roff[2][2];
#pragma unroll
    for (int ns = 0; ns < 2; ++ns) {
        int n = ns * 16 + nl;
        int s = (((n & 7) ^ (n >> 3)) & 7) << 2;
        roff[ns][0] = n * 32 + ((g * 8) ^ s);
        roff[ns][1] = n * 32 + ((g * 8 + 4) ^ s);
    }

    __syncthreads();   // z01L ready (full drain OK here, nothing in flight)

    // ---- prologue: fill 4-deep register pipeline (tiles 0..3)
    float rxv[4], ryv[4];
#pragma unroll
    for (int s = 0; s < 4; ++s) {
        rxv[s] = gsrc[(size_t)s * 32768];
        ryv[s] = gsrc[(size_t)s * 32768 + 1024];
    }
    {   // write tile 0 -> buf 0 (compiler inserts counted vmcnt)
        half2 hv; hv[0] = (_Float16)rxv[0]; hv[1] = (_Float16)ryv[0];
        *(half2*)&tile[0][woff] = hv;
    }
    asm volatile("s_waitcnt lgkmcnt(0)\n\ts_barrier" ::: "memory");

    f32x4 acc[2][2] = {};
    half4 zq0, zq1;

    // Per step T_: compute tile T_ (buf T_&3); issue loads tile T_+4 into
    // reg slot TT; cvt+write tile T_+1 (slot (TT+1)&3) AFTER the MFMAs so
    // the vmcnt wait overlaps compute; barrier gates next iter's reads.
#define ITER(T_, TT, ISSUE, WRITE)                                             \
    {                                                                          \
        if (ISSUE) {                                                           \
            rxv[TT] = gsrc[(size_t)((T_) + 4) * 32768];                        \
            ryv[TT] = gsrc[(size_t)((T_) + 4) * 32768 + 1024];                 \
        }                                                                      \
        if ((TT) == 0) {                                                       \
            zq0 = *(const half4*)&z01L[(T_) >> 2][w * 32 + nl][0];             \
            zq1 = *(const half4*)&z01L[(T_) >> 2][w * 32 + 16 + nl][0];        \
        }                                                                      \
        const _Float16* tb = &tile[(T_) & 3][0];                               \
        half4 lo0 = *(const half4*)&tb[roff[0][0]];                            \
        half4 hi0 = *(const half4*)&tb[roff[0][1]];                            \
        half4 lo1 = *(const half4*)&tb[roff[1][0]];                            \
        half4 hi1 = *(const half4*)&tb[roff[1][1]];                            \
        half8 bh0 = __builtin_shufflevector(lo0, hi0, 0,1,2,3,4,5,6,7);        \
        half8 bh1 = __builtin_shufflevector(lo1, hi1, 0,1,2,3,4,5,6,7);        \
        half8 a0 = z2v[0] * zq0[TT];                                           \
        half8 a1 = z2v[1] * zq1[TT];                                           \
        acc[0][0] = __builtin_amdgcn_mfma_f32_16x16x32_f16(a0, bh0, acc[0][0], 0, 0, 0); \
        acc[0][1] = __builtin_amdgcn_mfma_f32_16x16x32_f16(a0, bh1, acc[0][1], 0, 0, 0); \
        acc[1][0] = __builtin_amdgcn_mfma_f32_16x16x32_f16(a1, bh0, acc[1][0], 0, 0, 0); \
        acc[1][1] = __builtin_amdgcn_mfma_f32_16x16x32_f16(a1, bh1, acc[1][1], 0, 0, 0); \
        if (WRITE) {                                                           \
            half2 hv;                                                          \
            hv[0] = (_Float16)rxv[((TT) + 1) & 3];                             \
            hv[1] = (_Float16)ryv[((TT) + 1) & 3];                             \
            *(half2*)&tile[((T_) + 1) & 3][woff] = hv;                         \
        }                                                                      \
        asm volatile("s_waitcnt lgkmcnt(0)\n\ts_barrier" ::: "memory");        \
    }

    for (int grp = 0; grp < 15; ++grp) {
        const int t = grp * 4;
        ITER(t + 0, 0, 1, 1)
        ITER(t + 1, 1, 1, 1)
        ITER(t + 2, 2, 1, 1)
        ITER(t + 3, 3, 1, 1)
    }
    ITER(60, 0, 0, 1)
    ITER(61, 1, 0, 1)
    ITER(62, 2, 0, 1)
    ITER(63, 3, 0, 0)
#undef ITER

    // ---- epilogue: D layout col = lane&15, row = (lane>>4)*4 + r
    float* pout = partial + (size_t)ks * (256 * 1024);
#pragma unroll
    for (int ms = 0; ms < 2; ++ms)
#pragma unroll
        for (int ns = 0; ns < 2; ++ns)
#pragma unroll
            for (int r = 0; r < 4; ++r) {
                int brow = w * 32 + ms * 16 + g * 4 + r;
                int ncol = n0 + ns * 16 + nl;
                pout[brow * 1024 + ncol] = acc[ms][ns][r];
            }
}

// ---------------------------------------------------------------------------
// K2: h1[e] = relu(sum_s partial[s][e] + b1[e%1024]); h1 aliases partial[0]
// ---------------------------------------------------------------------------
__global__ __launch_bounds__(256) void k2_reduce(
    const float* __restrict__ partial, const float* __restrict__ b1,
    float* __restrict__ h1)
{
    int e = blockIdx.x * 256 + threadIdx.x;   // grid 1024 -> 262144 elements
    float s = 0.f;
#pragma unroll
    for (int sp = 0; sp < KSPLIT; ++sp) s += partial[(size_t)sp * 262144 + e];
    s += b1[e & 1023];
    h1[e] = fmaxf(s, 0.f);
}

// ---------------------------------------------------------------------------
// K3: layer 2 partials, M=256 K=1024 N=256; Mtile=32 Ntile=64 Ksplit=8
// ---------------------------------------------------------------------------
__global__ __launch_bounds__(256) void k3_layer2(
    const float* __restrict__ h1, const float* __restrict__ W2,
    float* __restrict__ p2)
{
    __shared__ float h1t[32 * 129];
    __shared__ float w2t[128 * 65];
    const int tid = threadIdx.x;
    const int m0 = blockIdx.x * 32, n0 = blockIdx.y * 64, k0 = blockIdx.z * 128;

    for (int idx = tid; idx < 32 * 128; idx += 256) {
        int m = idx >> 7, kk = idx & 127;
        h1t[m * 129 + kk] = h1[(m0 + m) * 1024 + k0 + kk];
    }
    for (int idx = tid; idx < 128 * 64; idx += 256) {
        int kk = idx >> 6, n = idx & 63;
        w2t[kk * 65 + n] = W2[(k0 + kk) * 256 + n0 + n];
    }
    __syncthreads();

    const int tn = tid & 63, tm = tid >> 6;   // tm 0..3
    float acc[8] = {};
    for (int kk = 0; kk < 128; ++kk) {
        float w = w2t[kk * 65 + tn];
#pragma unroll
        for (int r = 0; r < 8; ++r)
            acc[r] += h1t[(tm * 8 + r) * 129 + kk] * w;
    }
#pragma unroll
    for (int r = 0; r < 8; ++r)
        p2[blockIdx.z * 65536 + (m0 + tm * 8 + r) * 256 + n0 + tn] = acc[r];
}

// ---------------------------------------------------------------------------
// K4: h2 = relu(sum_s p2[s] + b2); out = h2 @ W3 + b3. One block per sample.
// ---------------------------------------------------------------------------
__global__ __launch_bounds__(256) void k4_final(
    const float* __restrict__ p2, const float* __restrict__ b2,
    const float* __restrict__ W3, const float* __restrict__ b3,
    float* __restrict__ out)
{
    __shared__ float pL[256 * 5];
    const int b = blockIdx.x, n = threadIdx.x;
    float s = 0.f;
#pragma unroll
    for (int sp = 0; sp < 8; ++sp) s += p2[sp * 65536 + b * 256 + n];
    float h2 = fmaxf(s + b2[n], 0.f);
#pragma unroll
    for (int c = 0; c < 4; ++c) pL[n * 5 + c] = h2 * W3[n * 4 + c];
    __syncthreads();

    const int lane = n & 63, w = n >> 6;      // wave w handles class c=w
    float v = pL[lane * 5 + w] + pL[(lane + 64) * 5 + w] +
              pL[(lane + 128) * 5 + w] + pL[(lane + 192) * 5 + w];
#pragma unroll
    for (int off = 32; off > 0; off >>= 1) v += __shfl_down(v, off);
    if (lane == 0) out[b * 4 + w] = v + b3[w];
}

extern "C" void kernel_launch(void* const* d_in, const int* in_sizes, int n_in,
                              void* d_out, int out_size, void* d_ws, size_t ws_size,
                              hipStream_t stream)
{
    (void)in_sizes; (void)n_in; (void)out_size; (void)ws_size;
    const float* x0 = (const float*)d_in[0];
    const float* x1 = (const float*)d_in[1];
    const float* x2 = (const float*)d_in[2];
    const float* W1 = (const float*)d_in[3];
    const float* b1 = (const float*)d_in[4];
    const float* W2 = (const float*)d_in[5];
    const float* b2 = (const float*)d_in[6];
    const float* W3 = (const float*)d_in[7];
    const float* b3 = (const float*)d_in[8];
    float* out = (float*)d_out;
    float* ws  = (float*)d_ws;

    // ws layout (floats): partial[16][262144] f32 = 16.8 MB (ws >= 33.5 MB
    // verified in R2). h1 aliases partial[0] (thread reads its own element
    // before overwriting); p2[8][65536] aliases partial[1] (dead after k2).
    float* partial = ws;
    float* h1 = ws;
    float* p2 = ws + 262144;

    k1_gemm  <<<dim3(512),     dim3(512), 0, stream>>>(x0, x1, x2, W1, partial);
    k2_reduce<<<dim3(1024),    dim3(256), 0, stream>>>(partial, b1, h1);
    k3_layer2<<<dim3(8, 4, 8), dim3(256), 0, stream>>>(h1, W2, p2);
    k4_final <<<dim3(256),     dim3(256), 0, stream>>>(p2, b2, W3, b3, out);
}